// Round 1
// baseline (475.140 us; speedup 1.0000x reference)
//
#include <hip/hip_runtime.h>
#include <hip/hip_bf16.h>
#include <cstdint>
#include <cstddef>

// ---------------- types ----------------
typedef short bf16x8 __attribute__((ext_vector_type(8)));   // 8 bf16 in 4 VGPRs
typedef float f32x4  __attribute__((ext_vector_type(4)));

#define HH 512
#define PP 256
#define LL 4096
#define BBATCH 16
#define MM (BBATCH * LL)          // 65536
#define NCHUNK 128                // chunks per sequence
#define SCHUNK 32                 // timesteps per chunk  (NCHUNK*SCHUNK == LL)

__device__ __forceinline__ unsigned short f2bf(float f) {
  union { float f; unsigned u; } v; v.f = f;
  unsigned r = (v.u + 0x7FFFu + ((v.u >> 16) & 1u)) >> 16;
  return (unsigned short)r;
}
__device__ __forceinline__ float bf2f(unsigned short b) {
  return __uint_as_float(((unsigned)b) << 16);
}

__device__ __forceinline__ void async16(const void* g, void* l) {
  __builtin_amdgcn_global_load_lds(
      (const __attribute__((address_space(1))) unsigned*)g,
      (__attribute__((address_space(3))) unsigned*)l, 16, 0, 0);
}

// ---------------- K0a: per-channel params ----------------
// lam layout (floats): [0,256) lam_re  [256,512) lam_im
//                      [512,768) a32_re [768,1024) a32_im
//                      [1024,1280) coef_re [1280,1536) coef_im
__global__ void precompute_params(const float* __restrict__ llr_,
                                  const float* __restrict__ lim_,
                                  const float* __restrict__ lstep_,
                                  float* __restrict__ lam) {
  int p = threadIdx.x;
  if (p >= PP) return;
  float Lr = -expf(llr_[p]);
  float Li = lim_[p];
  float st = expf(lstep_[p]);
  float mag = expf(Lr * st);
  float ang = Li * st;
  float lbr = mag * cosf(ang);
  float lbi = mag * sinf(ang);
  // coef = (Lambda_bar - 1) / Lambda
  float den = Lr * Lr + Li * Li;
  float nr = lbr - 1.f, ni = lbi;
  float cr = (nr * Lr + ni * Li) / den;
  float ci = (ni * Lr - nr * Li) / den;
  // a^32 = exp(32*Lr*st) * rot(32*ang)
  float m32 = expf(32.f * Lr * st);
  float a32r = m32 * cosf(32.f * ang);
  float a32i = m32 * sinf(32.f * ang);
  lam[p]            = lbr;
  lam[PP + p]       = lbi;
  lam[2 * PP + p]   = a32r;
  lam[3 * PP + p]   = a32i;
  lam[4 * PP + p]   = cr;
  lam[5 * PP + p]   = ci;
}

// ---------------- K0b: build bf16 weight matrices ----------------
// Bcat [512 rows(n), 512 cols(h)]: row p   = Re(B_bar[p,:]),
//                                  row P+p = Im(B_bar[p,:])
// Ccat [512 rows(h), 512 cols(k)]: col p   = 2*C_re[h,p],
//                                  col P+p = -2*C_im[h,p]
__global__ void build_weights(const float* __restrict__ B_re,
                              const float* __restrict__ B_im,
                              const float* __restrict__ C_re,
                              const float* __restrict__ C_im,
                              const float* __restrict__ lam,
                              unsigned short* __restrict__ Bcat,
                              unsigned short* __restrict__ Ccat) {
  int bid = blockIdx.x;   // 0..1023
  int tid = threadIdx.x;  // 0..255
  if (bid < 512) {
    int n = bid;
    int p = (n < PP) ? n : n - PP;
    float cr = lam[4 * PP + p], ci = lam[5 * PP + p];
    for (int c = tid; c < HH; c += 256) {
      float br = B_re[(size_t)p * HH + c];
      float bi = B_im[(size_t)p * HH + c];
      float v = (n < PP) ? (cr * br - ci * bi) : (cr * bi + ci * br);
      Bcat[(size_t)n * HH + c] = f2bf(v);
    }
  } else {
    int h = bid - 512;
    for (int c = tid; c < HH; c += 256) {
      float v = (c < PP) ? 2.f * C_re[(size_t)h * PP + c]
                         : -2.f * C_im[(size_t)h * PP + (c - PP)];
      Ccat[(size_t)h * HH + c] = f2bf(v);
    }
  }
}

// ---------------- K0c: x -> bf16 ----------------
__global__ __launch_bounds__(256) void cvt_x_bf16(const float* __restrict__ x,
                                                  unsigned short* __restrict__ xb) {
  const float4* x4 = (const float4*)x;
  ushort4* o4 = (ushort4*)xb;
  int stride = 2048 * 256;
  for (int i = blockIdx.x * 256 + threadIdx.x; i < (MM * HH / 4); i += stride) {
    float4 v = x4[i];
    ushort4 o;
    o.x = f2bf(v.x); o.y = f2bf(v.y); o.z = f2bf(v.z); o.w = f2bf(v.w);
    o4[i] = o;
  }
}

// ---------------- GEMM core (128x128 tile, BK=64, 4 waves) ----------------
// A [M,512] bf16 row-major, Bt [512,512] bf16 row-major ("B^T" layout).
// EPI 0: write bf16 C directly (Bu).
// EPI 1: t = acc + x*D; y = gelu(t); z = x + y; write bf16 z.
template <int EPI>
__global__ __launch_bounds__(256) void gemm_bt(const unsigned short* __restrict__ A,
                                               const unsigned short* __restrict__ Bt,
                                               const float* __restrict__ xf,
                                               const float* __restrict__ Dv,
                                               unsigned short* __restrict__ Cout) {
  __shared__ __align__(16) unsigned short Asl[128 * 64];
  __shared__ __align__(16) unsigned short Bsl[128 * 64];
  const int tid = threadIdx.x, lane = tid & 63, w = tid >> 6;
  const int bid = blockIdx.x;
  const int mt = bid >> 2, nt = bid & 3;
  const int m0 = mt * 128, n0 = nt * 128;
  const int r = lane & 15, g = lane >> 4;
  const int wm = (w >> 1) * 64, wn = (w & 1) * 64;

  f32x4 acc[4][4];
#pragma unroll
  for (int a = 0; a < 4; ++a)
#pragma unroll
    for (int b = 0; b < 4; ++b) acc[a][b] = (f32x4){0.f, 0.f, 0.f, 0.f};

  for (int kt = 0; kt < 512; kt += 64) {
#pragma unroll
    for (int j = 0; j < 4; ++j) {
      int idx = w * 4 + j;                    // 0..15
      int linear = (idx * 64 + lane) * 8;     // bf16 elem index in tile
      int row = linear >> 6;
      int col = linear & 63;
      async16(A + (size_t)(m0 + row) * 512 + kt + col, &Asl[idx * 512 + lane * 8]);
      async16(Bt + (size_t)(n0 + row) * 512 + kt + col, &Bsl[idx * 512 + lane * 8]);
    }
    asm volatile("s_waitcnt vmcnt(0)" ::: "memory");
    __syncthreads();
#pragma unroll
    for (int kk = 0; kk < 2; ++kk) {
      bf16x8 af[4], bv[4];
#pragma unroll
      for (int mi = 0; mi < 4; ++mi)
        af[mi] = *(const bf16x8*)&Asl[(wm + mi * 16 + r) * 64 + kk * 32 + g * 8];
#pragma unroll
      for (int ni = 0; ni < 4; ++ni)
        bv[ni] = *(const bf16x8*)&Bsl[(wn + ni * 16 + r) * 64 + kk * 32 + g * 8];
#pragma unroll
      for (int mi = 0; mi < 4; ++mi)
#pragma unroll
        for (int ni = 0; ni < 4; ++ni)
          acc[mi][ni] = __builtin_amdgcn_mfma_f32_16x16x32_bf16(
              af[mi], bv[ni], acc[mi][ni], 0, 0, 0);
    }
    __syncthreads();
  }

#pragma unroll
  for (int mi = 0; mi < 4; ++mi) {
#pragma unroll
    for (int ni = 0; ni < 4; ++ni) {
      int col = n0 + wn + ni * 16 + r;
      float Dh = (EPI == 1) ? Dv[col] : 0.f;
#pragma unroll
      for (int j = 0; j < 4; ++j) {
        int row = m0 + wm + mi * 16 + g * 4 + j;
        float v = acc[mi][ni][j];
        if (EPI == 0) {
          Cout[(size_t)row * 512 + col] = f2bf(v);
        } else {
          float xv = xf[(size_t)row * 512 + col];
          float t = v + xv * Dh;
          float u = 0.7978845608028654f * (t + 0.044715f * t * t * t);
          float e = __expf(2.f * u);
          float th = 1.f - 2.f / (e + 1.f);
          float y = 0.5f * t * (1.f + th);
          Cout[(size_t)row * 512 + col] = f2bf(xv + y);
        }
      }
    }
  }
}

// ---------------- scan pass A: per-chunk carries ----------------
__global__ __launch_bounds__(256) void scan_carry(const unsigned short* __restrict__ Bu,
                                                  const float* __restrict__ lam,
                                                  float* __restrict__ carry) {
  int bid = blockIdx.x;              // b*128 + c
  int b = bid >> 7, c = bid & 127;
  int p = threadIdx.x;
  float ar = lam[p], ai = lam[PP + p];
  float sr = 0.f, si = 0.f;
  size_t base = ((size_t)b * LL + (size_t)c * SCHUNK) * 512;
#pragma unroll
  for (int i = 0; i < SCHUNK; ++i) {
    float ur = bf2f(Bu[base + (size_t)i * 512 + p]);
    float ui = bf2f(Bu[base + (size_t)i * 512 + 256 + p]);
    float nr = ar * sr - ai * si + ur;
    float ni = ar * si + ai * sr + ui;
    sr = nr; si = ni;
  }
  carry[(size_t)bid * 512 + p] = sr;
  carry[(size_t)bid * 512 + 256 + p] = si;
}

// ---------------- scan pass B: sequential chain over chunks (in-place -> exclusive) ----------------
__global__ void scan_chain(float* __restrict__ carry, const float* __restrict__ lam) {
  int b = blockIdx.x;    // 16
  int p = threadIdx.x;   // 256
  float a32r = lam[2 * PP + p], a32i = lam[3 * PP + p];
  float sr = 0.f, si = 0.f;
  for (int c = 0; c < NCHUNK; ++c) {
    size_t idx = (size_t)(b * NCHUNK + c) * 512;
    float cr = carry[idx + p], ci = carry[idx + 256 + p];
    carry[idx + p] = sr;                 // exclusive: state entering chunk c
    carry[idx + 256 + p] = si;
    float nr = cr + a32r * sr - a32i * si;
    float ni = ci + a32r * si + a32i * sr;
    sr = nr; si = ni;
  }
}

// ---------------- scan pass C: recompute with carry-in, write xs bf16 ----------------
__global__ __launch_bounds__(256) void scan_final(const unsigned short* __restrict__ Bu,
                                                  const float* __restrict__ lam,
                                                  const float* __restrict__ carry,
                                                  unsigned short* __restrict__ xs) {
  int bid = blockIdx.x;
  int b = bid >> 7, c = bid & 127;
  int p = threadIdx.x;
  float ar = lam[p], ai = lam[PP + p];
  size_t cidx = (size_t)bid * 512;
  float sr = carry[cidx + p], si = carry[cidx + 256 + p];
  size_t base = ((size_t)b * LL + (size_t)c * SCHUNK) * 512;
#pragma unroll
  for (int i = 0; i < SCHUNK; ++i) {
    float ur = bf2f(Bu[base + (size_t)i * 512 + p]);
    float ui = bf2f(Bu[base + (size_t)i * 512 + 256 + p]);
    float nr = ar * sr - ai * si + ur;
    float ni = ar * si + ai * sr + ui;
    sr = nr; si = ni;
    xs[base + (size_t)i * 512 + p] = f2bf(sr);
    xs[base + (size_t)i * 512 + 256 + p] = f2bf(si);
  }
}

// ---------------- LayerNorm: one wave per row ----------------
__global__ __launch_bounds__(256) void ln_kernel(const unsigned short* __restrict__ z,
                                                 const float* __restrict__ scale,
                                                 const float* __restrict__ bias,
                                                 float* __restrict__ out) {
  int tid = threadIdx.x, lane = tid & 63, wv = tid >> 6;
  int gw = blockIdx.x * 4 + wv;      // 0..8191
  int c0 = lane * 8;
  float sc[8], bi[8];
#pragma unroll
  for (int j = 0; j < 8; ++j) { sc[j] = scale[c0 + j]; bi[j] = bias[c0 + j]; }
  for (int row = gw; row < MM; row += 8192) {
    uint4 zv = *(const uint4*)(z + (size_t)row * 512 + c0);
    float f[8];
    f[0] = __uint_as_float(zv.x << 16); f[1] = __uint_as_float(zv.x & 0xFFFF0000u);
    f[2] = __uint_as_float(zv.y << 16); f[3] = __uint_as_float(zv.y & 0xFFFF0000u);
    f[4] = __uint_as_float(zv.z << 16); f[5] = __uint_as_float(zv.z & 0xFFFF0000u);
    f[6] = __uint_as_float(zv.w << 16); f[7] = __uint_as_float(zv.w & 0xFFFF0000u);
    float s = 0.f, s2 = 0.f;
#pragma unroll
    for (int j = 0; j < 8; ++j) { s += f[j]; s2 += f[j] * f[j]; }
#pragma unroll
    for (int o = 32; o; o >>= 1) {
      s += __shfl_xor(s, o, 64);
      s2 += __shfl_xor(s2, o, 64);
    }
    float mean = s * (1.f / 512.f);
    float var = s2 * (1.f / 512.f) - mean * mean;
    float inv = rsqrtf(var + 1e-6f);
    float o8[8];
#pragma unroll
    for (int j = 0; j < 8; ++j) o8[j] = (f[j] - mean) * inv * sc[j] + bi[j];
    float4* op = (float4*)(out + (size_t)row * 512 + c0);
    op[0] = make_float4(o8[0], o8[1], o8[2], o8[3]);
    op[1] = make_float4(o8[4], o8[5], o8[6], o8[7]);
  }
}

// ---------------- launcher ----------------
extern "C" void kernel_launch(void* const* d_in, const int* in_sizes, int n_in,
                              void* d_out, int out_size, void* d_ws, size_t ws_size,
                              hipStream_t stream) {
  const float* x    = (const float*)d_in[0];
  const float* llr  = (const float*)d_in[1];
  const float* lim  = (const float*)d_in[2];
  const float* B_re = (const float*)d_in[3];
  const float* B_im = (const float*)d_in[4];
  const float* C_re = (const float*)d_in[5];
  const float* C_im = (const float*)d_in[6];
  const float* Dv   = (const float*)d_in[7];
  const float* lstep= (const float*)d_in[8];
  const float* lnsc = (const float*)d_in[9];
  const float* lnbi = (const float*)d_in[10];
  float* out = (float*)d_out;

  char* ws = (char*)d_ws;
  // layout:
  //   [0, 64MB)        x_bf16, later overwritten by xs_bf16
  //   [64MB, 128MB)    Bu bf16, later overwritten by z bf16
  //   then Bcat (512KB), Ccat (512KB), lam (6KB), carry (4MB)
  unsigned short* xb   = (unsigned short*)(ws);
  unsigned short* bu   = (unsigned short*)(ws + 67108864);
  unsigned short* bcat = (unsigned short*)(ws + 134217728);
  unsigned short* ccat = (unsigned short*)(ws + 134742016);
  float* lam           = (float*)(ws + 135266304);
  float* carry         = (float*)(ws + 135272448);

  precompute_params<<<1, 256, 0, stream>>>(llr, lim, lstep, lam);
  build_weights<<<1024, 256, 0, stream>>>(B_re, B_im, C_re, C_im, lam, bcat, ccat);
  cvt_x_bf16<<<2048, 256, 0, stream>>>(x, xb);
  gemm_bt<0><<<2048, 256, 0, stream>>>(xb, bcat, nullptr, nullptr, bu);
  scan_carry<<<2048, 256, 0, stream>>>(bu, lam, carry);
  scan_chain<<<16, 256, 0, stream>>>(carry, lam);
  scan_final<<<2048, 256, 0, stream>>>(bu, lam, carry, xb);   // xs over x_bf16
  gemm_bt<1><<<2048, 256, 0, stream>>>(xb, ccat, x, Dv, bu);  // z over Bu
  ln_kernel<<<2048, 256, 0, stream>>>(bu, lnsc, lnbi, out);
}